// Round 5
// baseline (8496.686 us; speedup 1.0000x reference)
//
#include <hip/hip_runtime.h>
#include <cmath>

namespace {
constexpr int BPTS  = 16384;
constexpr int NPOSE = 32;
constexpr int KV    = 8;
constexpr int HD    = 256;
constexpr int TM    = 128;      // points per block

constexpr size_t OFF_XLOCAL = 0;
constexpr size_t OFF_XLA    = (size_t)BPTS * 3;
constexpr size_t OFF_MINENC = OFF_XLA + (size_t)NPOSE * BPTS * 3;
constexpr size_t OFF_POSEQ  = OFF_MINENC + (size_t)BPTS * NPOSE;
constexpr size_t OFF_CLASS  = OFF_POSEQ + (size_t)BPTS * 16;
constexpr size_t OFF_PRED   = OFF_CLASS + (size_t)BPTS;
constexpr size_t OFF_VECQ   = OFF_PRED + (size_t)BPTS * NPOSE;

// workspace (f16 elements): weight fragment buffers, hi/lo split
constexpr size_t WS_W0H = 0;         // 16 cht * 2 kc * 64 lanes * 8 e
constexpr size_t WS_W0L = 16384;
constexpr size_t WS_W1H = 32768;     // 16 cht * 8 kc * 512
constexpr size_t WS_W1L = 98304;
constexpr size_t WS_W2H = 163840;
constexpr size_t WS_W2L = 229376;
}

typedef _Float16 f16;
typedef __attribute__((ext_vector_type(4))) _Float16 f16x4;
typedef __attribute__((ext_vector_type(8))) _Float16 f16x8;
typedef __attribute__((ext_vector_type(4))) float    f32x4;

#define MFMA16(a, b, c) __builtin_amdgcn_mfma_f32_16x16x32_f16((a), (b), (c), 0, 0, 0)

// ---- weight prep: split fp32 W[k][ch] into hi/lo f16 A-fragments.
// Fragment layout: idx = ((cht*KC + kc)*64 + lane)*8 + e, holding
// W[k = kc*32 + (lane>>4)*8 + e][ch = cht*16 + (lane&15)].
// Convention (m = lane&15, k = (lane>>4)*8+e) HW-verified by round-4 pass.
__global__ __launch_bounds__(256)
void prep_w0(const float* __restrict__ w, f16* __restrict__ dh, f16* __restrict__ dl)
{
    int i = blockIdx.x * 256 + threadIdx.x;      // 16384 total
    int e  = i & 7;
    int l  = (i >> 3) & 63;
    int kc = (i >> 9) & 1;
    int nt = i >> 10;
    int k   = kc * 32 + ((l >> 4) << 3) + e;
    int col = nt * 16 + (l & 15);
    float v = (k < 39) ? w[k * HD + col] : 0.f;
    f16 hi = (f16)v;
    dh[i] = hi;
    dl[i] = (f16)(v - (float)hi);
}

__global__ __launch_bounds__(256)
void prep_whd(const float* __restrict__ w, f16* __restrict__ dh, f16* __restrict__ dl)
{
    int i = blockIdx.x * 256 + threadIdx.x;      // 65536 total
    int e  = i & 7;
    int l  = (i >> 3) & 63;
    int kc = (i >> 9) & 7;
    int nt = i >> 12;
    int k   = kc * 32 + ((l >> 4) << 3) + e;
    int col = nt * 16 + (l & 15);
    float v = w[k * HD + col];
    f16 hi = (f16)v;
    dh[i] = hi;
    dl[i] = (f16)(v - (float)hi);
}

// swizzled byte address inside a 128-col half-plane: row p (0..127), cbyte 0..255
__device__ __forceinline__ int bswz(int p, int cbyte) {
    return p * 256 + (cbyte ^ ((p & 7) << 4));
}

__global__ __launch_bounds__(512, 4)
void mlp_kernel(const float* __restrict__ x_world,
                const float* __restrict__ inv_poses,
                const float* __restrict__ b0, const float* __restrict__ b1,
                const float* __restrict__ b2, const float* __restrict__ w3,
                const float* __restrict__ b3, const f16* __restrict__ wf,
                float* __restrict__ out)
{
    __shared__ char  lds[65536];        // bufh [0,32K) | bufl [32K,64K); feat overlaps head
    __shared__ float predp[TM][2];

    f16* feath = (f16*)lds;             // [128][40] f16 = 10 KB
    f16* featl = (f16*)(lds + 10240);   // 10 KB

    const int tid  = threadIdx.x;
    const int lane = tid & 63;
    const int wid  = tid >> 6;          // 8 waves
    const int l15  = lane & 15;
    const int g    = lane >> 4;
    const int pg   = wid & 3;           // point-group: points pg*32 .. +32
    const int nb   = wid >> 2;          // channel-half selector

    const int bid   = blockIdx.x;
    const int n_idx = bid >> 7;         // 128 blocks per pose
    const int bbase = (bid & 127) * TM;

    // wave's channel tiles: nb=0 -> {0,1,2,3, 8,9,10,11}; nb=1 -> {4..7, 12..15}
    // i<4 live in phase-A cols (0..127), i>=4 in phase-B (128..255)
    auto chtof = [&](int i) { return nb * 4 + (i & 3) + ((i >> 2) << 3); };

    // ---- pose transform + positional encoding (4 threads per point) ----
    {
        const int p   = tid >> 2;       // 0..127
        const int sub = tid & 3;
        const int b   = bbase + p;
        const float xw0 = x_world[b*3+0], xw1 = x_world[b*3+1], xw2 = x_world[b*3+2];
        const float* P = inv_poses + n_idx * 16;
        float xl[3];
        #pragma unroll
        for (int x = 0; x < 3; ++x)
            xl[x] = P[x*4+3] + P[x*4+0]*xw0 + P[x*4+1]*xw1 + P[x*4+2]*xw2;

        auto put = [&](int c, float v) {
            f16 hi = (f16)v;
            feath[p*40 + c] = hi;
            featl[p*40 + c] = (f16)(v - (float)hi);
        };
        if (sub == 0) {
            float* xla = out + OFF_XLA + ((size_t)n_idx * BPTS + b) * 3;
            #pragma unroll
            for (int x = 0; x < 3; ++x) { xla[x] = xl[x]; put(x, xl[x]); }
            put(39, 0.f);               // k-pad
        }
        #pragma unroll
        for (int t = 0; t < 3; ++t) {   // 12 sin/cos jobs, 3 per sub
            int j = sub * 3 + t;
            int o = j >> 1, fn = j & 1;
            float s = (float)(1 << o);
            #pragma unroll
            for (int x = 0; x < 3; ++x) {
                float a = xl[x] * s;
                put(3 + 6*o + 3*fn + x, fn ? cosf(a) : sinf(a));
            }
        }
    }
    __syncthreads();

    f32x4 acc[2][8];                    // [pt-tile][i]: 32 points x 128 channels

    auto init_bias = [&](const float* bias) {
        #pragma unroll
        for (int i = 0; i < 8; ++i) {
            int cht = chtof(i);
            f32x4 bv = *(const f32x4*)(bias + cht * 16 + g * 4);
            acc[0][i] = bv; acc[1][i] = bv;
        }
    };

    // ---- layer 0: feat(39, padded) -> acc ----
    init_bias(b0);
    {
        const f16x8 z = {};
        #pragma unroll
        for (int kc = 0; kc < 2; ++kc) {
            f16x8 ah[2], al[2];
            #pragma unroll
            for (int pt = 0; pt < 2; ++pt) {
                int p = (pg * 2 + pt) * 16 + l15;
                if (kc == 0) {
                    ah[pt] = *(const f16x8*)&feath[p*40 + g*8];
                    al[pt] = *(const f16x8*)&featl[p*40 + g*8];
                } else if (g == 0) {
                    ah[pt] = *(const f16x8*)&feath[p*40 + 32];
                    al[pt] = *(const f16x8*)&featl[p*40 + 32];
                } else { ah[pt] = z; al[pt] = z; }
            }
            #pragma unroll
            for (int i = 0; i < 8; ++i) {
                int cht = chtof(i);
                int off = ((cht * 2 + kc) * 64 + lane) * 8;
                f16x8 wh = *(const f16x8*)(wf + WS_W0H + off);
                f16x8 wl = *(const f16x8*)(wf + WS_W0L + off);
                #pragma unroll
                for (int pt = 0; pt < 2; ++pt) {
                    acc[pt][i] = MFMA16(wh, ah[pt], acc[pt][i]);
                    acc[pt][i] = MFMA16(wl, ah[pt], acc[pt][i]);
                    acc[pt][i] = MFMA16(wh, al[pt], acc[pt][i]);
                }
            }
        }
    }

    auto packpair = [&](f32x4 a, f16x4& hv, f16x4& lv) {
        float v0 = fmaxf(a[0], 0.f), v1 = fmaxf(a[1], 0.f);
        float v2 = fmaxf(a[2], 0.f), v3 = fmaxf(a[3], 0.f);
        f16 h0 = (f16)v0, h1 = (f16)v1, h2 = (f16)v2, h3 = (f16)v3;
        hv = (f16x4){h0, h1, h2, h3};
        lv = (f16x4){(f16)(v0 - (float)h0), (f16)(v1 - (float)h1),
                     (f16)(v2 - (float)h2), (f16)(v3 - (float)h3)};
    };
    auto stfrag = [&](int pt, int cht, f16x4 hv, f16x4 lv) {
        int p    = (pg * 2 + pt) * 16 + l15;
        int byte = bswz(p, (cht & 7) * 32 + g * 8);   // 4 consecutive channels, b64
        *(f16x4*)(lds + byte)         = hv;
        *(f16x4*)(lds + 32768 + byte) = lv;
    };
    auto phase = [&](const f16* wfh, const f16* wfl, int ph) {
        #pragma unroll
        for (int kc4 = 0; kc4 < 4; ++kc4) {
            f16x8 bh[2], bl[2];
            #pragma unroll
            for (int pt = 0; pt < 2; ++pt) {
                int p    = (pg * 2 + pt) * 16 + l15;
                int byte = bswz(p, kc4 * 64 + g * 16);
                bh[pt] = *(const f16x8*)(lds + byte);
                bl[pt] = *(const f16x8*)(lds + 32768 + byte);
            }
            int kcg = ph * 4 + kc4;
            #pragma unroll
            for (int i = 0; i < 8; ++i) {
                int cht = chtof(i);
                int off = ((cht * 8 + kcg) * 64 + lane) * 8;
                f16x8 wh = *(const f16x8*)(wfh + off);
                f16x8 wl = *(const f16x8*)(wfl + off);
                #pragma unroll
                for (int pt = 0; pt < 2; ++pt) {
                    acc[pt][i] = MFMA16(wh, bh[pt], acc[pt][i]);
                    acc[pt][i] = MFMA16(wl, bh[pt], acc[pt][i]);
                    acc[pt][i] = MFMA16(wh, bl[pt], acc[pt][i]);
                }
            }
        }
    };

    // ---- hidden layer: acc(h_prev) -> stores -> acc(h_next), two k-phases ----
    auto hd_layer = [&](const float* bias, const f16* wfh, const f16* wfl) {
        f16x4 hh[2][4], hl[2][4];                 // held: phase-B half (32 VGPR)
        #pragma unroll
        for (int pt = 0; pt < 2; ++pt)
            #pragma unroll
            for (int q = 0; q < 4; ++q)
                packpair(acc[pt][q + 4], hh[pt][q], hl[pt][q]);
        __syncthreads();                          // prior buf/feat reads done
        #pragma unroll
        for (int pt = 0; pt < 2; ++pt)            // store phase-A half from acc
            #pragma unroll
            for (int q = 0; q < 4; ++q) {
                f16x4 a, b;
                packpair(acc[pt][q], a, b);
                stfrag(pt, chtof(q), a, b);
            }
        __syncthreads();
        init_bias(bias);
        phase(wfh, wfl, 0);                       // consume cols 0..127
        __syncthreads();                          // phase-A reads done
        #pragma unroll
        for (int pt = 0; pt < 2; ++pt)            // store phase-B half (cols 128..255)
            #pragma unroll
            for (int q = 0; q < 4; ++q)
                stfrag(pt, chtof(q + 4), hh[pt][q], hl[pt][q]);
        __syncthreads();
        phase(wfh, wfl, 1);                       // consume cols 128..255
    };

    hd_layer(b1, wf + WS_W1H, wf + WS_W1L);
    hd_layer(b2, wf + WS_W2H, wf + WS_W2L);

    // ---- layer 3 from registers: pred[point] = sum_ch relu(h2)*w3[ch] ----
    {
        float pp[2] = {0.f, 0.f};
        #pragma unroll
        for (int i = 0; i < 8; ++i) {
            int cht = chtof(i);
            f32x4 wv = *(const f32x4*)(w3 + cht * 16 + g * 4);
            #pragma unroll
            for (int pt = 0; pt < 2; ++pt)
                #pragma unroll
                for (int r = 0; r < 4; ++r)
                    pp[pt] = fmaf(fmaxf(acc[pt][i][r], 0.f), wv[r], pp[pt]);
        }
        #pragma unroll
        for (int pt = 0; pt < 2; ++pt) {          // reduce over g (channels)
            pp[pt] += __shfl_xor(pp[pt], 16);
            pp[pt] += __shfl_xor(pp[pt], 32);
        }
        if (g == 0) {
            #pragma unroll
            for (int pt = 0; pt < 2; ++pt)
                predp[(pg * 2 + pt) * 16 + l15][nb] = pp[pt];
        }
    }
    __syncthreads();
    if (tid < TM) {
        float p = predp[tid][0] + predp[tid][1] + b3[0];
        out[OFF_PRED + (size_t)(bbase + tid) * NPOSE + n_idx] = p;
    }
}

__global__ __launch_bounds__(256)
void select_kernel(const float* __restrict__ x_world,
                   const float* __restrict__ inv_poses,
                   const float* __restrict__ vector,
                   float* __restrict__ out)
{
    const int b = blockIdx.x * 256 + threadIdx.x;
    if (b >= BPTS) return;

    const float* pr = out + OFF_PRED + (size_t)b * NPOSE;
    float best = pr[0];
    int idx = 0;
    #pragma unroll
    for (int n = 1; n < NPOSE; ++n) {           // first-occurrence min == jnp.argmin
        float v = pr[n];
        if (v < best) { best = v; idx = n; }
    }

    float* me = out + OFF_MINENC + (size_t)b * NPOSE;
    #pragma unroll
    for (int n = 0; n < NPOSE; ++n) me[n] = (n == idx) ? 1.f : 0.f;

    const float* P = inv_poses + idx * 16;
    float* pq = out + OFF_POSEQ + (size_t)b * 16;
    #pragma unroll
    for (int m = 0; m < 16; ++m) pq[m] = P[m];

    const float xw0 = x_world[b*3+0], xw1 = x_world[b*3+1], xw2 = x_world[b*3+2];
    float* xl = out + OFF_XLOCAL + (size_t)b * 3;
    #pragma unroll
    for (int x = 0; x < 3; ++x)
        xl[x] = P[x*4+3] + P[x*4+0]*xw0 + P[x*4+1]*xw1 + P[x*4+2]*xw2;

    out[OFF_CLASS + b] = (float)idx;

    const float* vq = vector + idx * KV;
    float* ov = out + OFF_VECQ + (size_t)b * KV;
    #pragma unroll
    for (int m = 0; m < KV; ++m) ov[m] = vq[m];
}

extern "C" void kernel_launch(void* const* d_in, const int* in_sizes, int n_in,
                              void* d_out, int out_size, void* d_ws, size_t ws_size,
                              hipStream_t stream)
{
    const float* x_world   = (const float*)d_in[0];
    const float* inv_poses = (const float*)d_in[1];
    const float* vector    = (const float*)d_in[2];
    const float* w0 = (const float*)d_in[3];
    const float* b0 = (const float*)d_in[4];
    const float* w1 = (const float*)d_in[5];
    const float* b1 = (const float*)d_in[6];
    const float* w2 = (const float*)d_in[7];
    const float* b2 = (const float*)d_in[8];
    const float* w3 = (const float*)d_in[9];
    const float* b3 = (const float*)d_in[10];
    float* out = (float*)d_out;
    f16*   wf  = (f16*)d_ws;            // 576 KB of fragment buffers

    prep_w0 <<<dim3(64),  dim3(256), 0, stream>>>(w0, wf + WS_W0H, wf + WS_W0L);
    prep_whd<<<dim3(256), dim3(256), 0, stream>>>(w1, wf + WS_W1H, wf + WS_W1L);
    prep_whd<<<dim3(256), dim3(256), 0, stream>>>(w2, wf + WS_W2H, wf + WS_W2L);

    mlp_kernel<<<dim3(NPOSE * BPTS / TM), dim3(512), 0, stream>>>(
        x_world, inv_poses, b0, b1, b2, w3, b3, wf, out);
    select_kernel<<<dim3(BPTS / 256), dim3(256), 0, stream>>>(
        x_world, inv_poses, vector, out);
}

// Round 6
// 737.073 us; speedup vs baseline: 11.5276x; 11.5276x over previous
//
#include <hip/hip_runtime.h>
#include <cmath>

namespace {
constexpr int BPTS  = 16384;
constexpr int NPOSE = 32;
constexpr int KV    = 8;
constexpr int HD    = 256;
constexpr int TM    = 64;       // points per block

constexpr size_t OFF_XLOCAL = 0;
constexpr size_t OFF_XLA    = (size_t)BPTS * 3;
constexpr size_t OFF_MINENC = OFF_XLA + (size_t)NPOSE * BPTS * 3;
constexpr size_t OFF_POSEQ  = OFF_MINENC + (size_t)BPTS * NPOSE;
constexpr size_t OFF_CLASS  = OFF_POSEQ + (size_t)BPTS * 16;
constexpr size_t OFF_PRED   = OFF_CLASS + (size_t)BPTS;
constexpr size_t OFF_VECQ   = OFF_PRED + (size_t)BPTS * NPOSE;

// workspace (f16 elements): weight fragment buffers, hi/lo split
constexpr size_t WS_W0H = 0;         // 16 cht * 2 kc * 64 lanes * 8 e
constexpr size_t WS_W0L = 16384;
constexpr size_t WS_W1H = 32768;     // 16 cht * 8 kc * 512
constexpr size_t WS_W1L = 98304;
constexpr size_t WS_W2H = 163840;
constexpr size_t WS_W2L = 229376;
}

typedef _Float16 f16;
typedef __attribute__((ext_vector_type(4))) _Float16 f16x4;
typedef __attribute__((ext_vector_type(8))) _Float16 f16x8;
typedef __attribute__((ext_vector_type(4))) float    f32x4;

#define MFMA16(a, b, c) __builtin_amdgcn_mfma_f32_16x16x32_f16((a), (b), (c), 0, 0, 0)

// ---- weight prep: split fp32 W[k][ch] into hi/lo f16 A-fragments.
// Fragment layout: idx = ((cht*KC + kc)*64 + lane)*8 + e, holding
// W[k = kc*32 + (lane>>4)*8 + e][ch = cht*16 + (lane&15)].
// Convention (m = lane&15, k = (lane>>4)*8+e) HW-verified by round-4 pass.
__global__ __launch_bounds__(256)
void prep_w0(const float* __restrict__ w, f16* __restrict__ dh, f16* __restrict__ dl)
{
    int i = blockIdx.x * 256 + threadIdx.x;      // 16384 total
    int e  = i & 7;
    int l  = (i >> 3) & 63;
    int kc = (i >> 9) & 1;
    int nt = i >> 10;
    int k   = kc * 32 + ((l >> 4) << 3) + e;
    int col = nt * 16 + (l & 15);
    float v = (k < 39) ? w[k * HD + col] : 0.f;
    f16 hi = (f16)v;
    dh[i] = hi;
    dl[i] = (f16)(v - (float)hi);
}

__global__ __launch_bounds__(256)
void prep_whd(const float* __restrict__ w, f16* __restrict__ dh, f16* __restrict__ dl)
{
    int i = blockIdx.x * 256 + threadIdx.x;      // 65536 total
    int e  = i & 7;
    int l  = (i >> 3) & 63;
    int kc = (i >> 9) & 7;
    int nt = i >> 12;
    int k   = kc * 32 + ((l >> 4) << 3) + e;
    int col = nt * 16 + (l & 15);
    float v = w[k * HD + col];
    f16 hi = (f16)v;
    dh[i] = hi;
    dl[i] = (f16)(v - (float)hi);
}

// swizzled byte address inside the 128-col half-plane: row p (0..63), cbyte 0..255
__device__ __forceinline__ int bswz(int p, int cbyte) {
    return p * 256 + (cbyte ^ ((p & 7) << 4));
}

__global__ __launch_bounds__(512, 4)
void mlp_kernel(const float* __restrict__ x_world,
                const float* __restrict__ inv_poses,
                const float* __restrict__ b0, const float* __restrict__ b1,
                const float* __restrict__ b2, const float* __restrict__ w3,
                const float* __restrict__ b3, const f16* __restrict__ wf,
                float* __restrict__ out)
{
    __shared__ char  lds[32768];        // bufh [0,16K) | bufl [16K,32K); feat overlaps head
    __shared__ float predp[TM][2];

    f16* feath = (f16*)lds;             // [64][40] f16 = 5 KB
    f16* featl = (f16*)(lds + 5120);    // 5 KB

    const int tid  = threadIdx.x;
    const int lane = tid & 63;
    const int wid  = tid >> 6;          // 8 waves
    const int l15  = lane & 15;
    const int g    = lane >> 4;
    const int pg   = wid & 3;           // point-group: points pg*16 .. +16
    const int nb   = wid >> 2;          // channel-half selector
    const int p_me = pg * 16 + l15;     // this lane's point (B-frag / D-col)

    const int bid   = blockIdx.x;
    const int n_idx = bid >> 8;         // 256 blocks per pose
    const int bbase = (bid & 255) * TM;

    // wave's channel tiles: nb=0 -> {0,1,2,3, 8,9,10,11}; nb=1 -> {4..7, 12..15}
    // i<4 live in phase-A cols (0..127), i>=4 in phase-B (128..255)
    auto chtof = [&](int i) { return nb * 4 + (i & 3) + ((i >> 2) << 3); };

    // ---- pose transform + positional encoding (8 threads per point) ----
    {
        const int p   = tid >> 3;       // 0..63
        const int sub = tid & 7;
        const int b   = bbase + p;
        const float xw0 = x_world[b*3+0], xw1 = x_world[b*3+1], xw2 = x_world[b*3+2];
        const float* P = inv_poses + n_idx * 16;
        float xl[3];
        #pragma unroll
        for (int x = 0; x < 3; ++x)
            xl[x] = P[x*4+3] + P[x*4+0]*xw0 + P[x*4+1]*xw1 + P[x*4+2]*xw2;

        auto put = [&](int c, float v) {
            f16 hi = (f16)v;
            feath[p*40 + c] = hi;
            featl[p*40 + c] = (f16)(v - (float)hi);
        };
        if (sub == 0) {
            float* xla = out + OFF_XLA + ((size_t)n_idx * BPTS + b) * 3;
            #pragma unroll
            for (int x = 0; x < 3; ++x) { xla[x] = xl[x]; put(x, xl[x]); }
            put(39, 0.f);               // k-pad
        }
        #pragma unroll
        for (int t = 0; t < 2; ++t) {   // 12 sin/cos jobs: j = sub, and j = sub+8 (sub<4)
            int j = sub + 8*t;
            if (j < 12) {
                int o = j >> 1, fn = j & 1;
                float s = (float)(1 << o);
                #pragma unroll
                for (int x = 0; x < 3; ++x) {
                    float a = xl[x] * s;
                    put(3 + 6*o + 3*fn + x, fn ? cosf(a) : sinf(a));
                }
            }
        }
    }
    __syncthreads();

    f32x4 acc[8];                       // 16 points x 128 channels per wave (32 VGPR)

    auto init_bias = [&](const float* bias) {
        #pragma unroll
        for (int i = 0; i < 8; ++i)
            acc[i] = *(const f32x4*)(bias + chtof(i) * 16 + g * 4);
    };

    // ---- layer 0: feat(39, padded) -> acc ----
    init_bias(b0);
    {
        const f16x8 z = {};
        #pragma unroll
        for (int kc = 0; kc < 2; ++kc) {
            f16x8 ah, al;
            if (kc == 0) {
                ah = *(const f16x8*)&feath[p_me*40 + g*8];
                al = *(const f16x8*)&featl[p_me*40 + g*8];
            } else if (g == 0) {
                ah = *(const f16x8*)&feath[p_me*40 + 32];
                al = *(const f16x8*)&featl[p_me*40 + 32];
            } else { ah = z; al = z; }
            #pragma unroll
            for (int i = 0; i < 8; ++i) {
                int off = ((chtof(i) * 2 + kc) * 64 + lane) * 8;
                f16x8 wh = *(const f16x8*)(wf + WS_W0H + off);
                f16x8 wl = *(const f16x8*)(wf + WS_W0L + off);
                acc[i] = MFMA16(wh, ah, acc[i]);
                acc[i] = MFMA16(wl, ah, acc[i]);
                acc[i] = MFMA16(wh, al, acc[i]);
            }
        }
    }

    auto packpair = [&](f32x4 a, f16x4& hv, f16x4& lv) {
        float v0 = fmaxf(a[0], 0.f), v1 = fmaxf(a[1], 0.f);
        float v2 = fmaxf(a[2], 0.f), v3 = fmaxf(a[3], 0.f);
        f16 h0 = (f16)v0, h1 = (f16)v1, h2 = (f16)v2, h3 = (f16)v3;
        hv = (f16x4){h0, h1, h2, h3};
        lv = (f16x4){(f16)(v0 - (float)h0), (f16)(v1 - (float)h1),
                     (f16)(v2 - (float)h2), (f16)(v3 - (float)h3)};
    };
    auto stfrag = [&](int cht, f16x4 hv, f16x4 lv) {
        int byte = bswz(p_me, (cht & 7) * 32 + g * 8);  // 4 consecutive channels, b64
        *(f16x4*)(lds + byte)         = hv;
        *(f16x4*)(lds + 16384 + byte) = lv;
    };
    auto phase = [&](const f16* wfh, const f16* wfl, int ph) {
        #pragma unroll
        for (int kc4 = 0; kc4 < 4; ++kc4) {
            int byte = bswz(p_me, kc4 * 64 + g * 16);
            f16x8 bh = *(const f16x8*)(lds + byte);
            f16x8 bl = *(const f16x8*)(lds + 16384 + byte);
            int kcg = ph * 4 + kc4;
            #pragma unroll
            for (int i = 0; i < 8; ++i) {
                int off = ((chtof(i) * 8 + kcg) * 64 + lane) * 8;
                f16x8 wh = *(const f16x8*)(wfh + off);
                f16x8 wl = *(const f16x8*)(wfl + off);
                acc[i] = MFMA16(wh, bh, acc[i]);
                acc[i] = MFMA16(wl, bh, acc[i]);
                acc[i] = MFMA16(wh, bl, acc[i]);
            }
        }
    };

    // ---- hidden layer: acc(h_prev) -> stores -> acc(h_next), two k-phases ----
    auto hd_layer = [&](const float* bias, const f16* wfh, const f16* wfl) {
        f16x4 hh[4], hl[4];                       // held: phase-B half (8 VGPR)
        #pragma unroll
        for (int q = 0; q < 4; ++q)
            packpair(acc[q + 4], hh[q], hl[q]);
        __syncthreads();                          // prior buf/feat reads done
        #pragma unroll
        for (int q = 0; q < 4; ++q) {             // store phase-A half from acc
            f16x4 a, b;
            packpair(acc[q], a, b);
            stfrag(chtof(q), a, b);
        }
        __syncthreads();
        init_bias(bias);
        phase(wfh, wfl, 0);                       // consume cols 0..127
        __syncthreads();                          // phase-A reads done
        #pragma unroll
        for (int q = 0; q < 4; ++q)               // store phase-B half (cols 128..255)
            stfrag(chtof(q + 4), hh[q], hl[q]);
        __syncthreads();
        phase(wfh, wfl, 1);                       // consume cols 128..255
    };

    hd_layer(b1, wf + WS_W1H, wf + WS_W1L);
    hd_layer(b2, wf + WS_W2H, wf + WS_W2L);

    // ---- layer 3 from registers: pred[point] = sum_ch relu(h2)*w3[ch] ----
    {
        float pp = 0.f;
        #pragma unroll
        for (int i = 0; i < 8; ++i) {
            f32x4 wv = *(const f32x4*)(w3 + chtof(i) * 16 + g * 4);
            #pragma unroll
            for (int r = 0; r < 4; ++r)
                pp = fmaf(fmaxf(acc[i][r], 0.f), wv[r], pp);
        }
        pp += __shfl_xor(pp, 16);                 // reduce over g (channel groups)
        pp += __shfl_xor(pp, 32);
        if (g == 0) predp[p_me][nb] = pp;
    }
    __syncthreads();
    if (tid < TM) {
        float p = predp[tid][0] + predp[tid][1] + b3[0];
        out[OFF_PRED + (size_t)(bbase + tid) * NPOSE + n_idx] = p;
    }
}

__global__ __launch_bounds__(256)
void select_kernel(const float* __restrict__ x_world,
                   const float* __restrict__ inv_poses,
                   const float* __restrict__ vector,
                   float* __restrict__ out)
{
    const int b = blockIdx.x * 256 + threadIdx.x;
    if (b >= BPTS) return;

    const float* pr = out + OFF_PRED + (size_t)b * NPOSE;
    float best = pr[0];
    int idx = 0;
    #pragma unroll
    for (int n = 1; n < NPOSE; ++n) {           // first-occurrence min == jnp.argmin
        float v = pr[n];
        if (v < best) { best = v; idx = n; }
    }

    float* me = out + OFF_MINENC + (size_t)b * NPOSE;
    #pragma unroll
    for (int n = 0; n < NPOSE; ++n) me[n] = (n == idx) ? 1.f : 0.f;

    const float* P = inv_poses + idx * 16;
    float* pq = out + OFF_POSEQ + (size_t)b * 16;
    #pragma unroll
    for (int m = 0; m < 16; ++m) pq[m] = P[m];

    const float xw0 = x_world[b*3+0], xw1 = x_world[b*3+1], xw2 = x_world[b*3+2];
    float* xl = out + OFF_XLOCAL + (size_t)b * 3;
    #pragma unroll
    for (int x = 0; x < 3; ++x)
        xl[x] = P[x*4+3] + P[x*4+0]*xw0 + P[x*4+1]*xw1 + P[x*4+2]*xw2;

    out[OFF_CLASS + b] = (float)idx;

    const float* vq = vector + idx * KV;
    float* ov = out + OFF_VECQ + (size_t)b * KV;
    #pragma unroll
    for (int m = 0; m < KV; ++m) ov[m] = vq[m];
}

extern "C" void kernel_launch(void* const* d_in, const int* in_sizes, int n_in,
                              void* d_out, int out_size, void* d_ws, size_t ws_size,
                              hipStream_t stream)
{
    const float* x_world   = (const float*)d_in[0];
    const float* inv_poses = (const float*)d_in[1];
    const float* vector    = (const float*)d_in[2];
    const float* w0 = (const float*)d_in[3];
    const float* b0 = (const float*)d_in[4];
    const float* w1 = (const float*)d_in[5];
    const float* b1 = (const float*)d_in[6];
    const float* w2 = (const float*)d_in[7];
    const float* b2 = (const float*)d_in[8];
    const float* w3 = (const float*)d_in[9];
    const float* b3 = (const float*)d_in[10];
    float* out = (float*)d_out;
    f16*   wf  = (f16*)d_ws;            // 576 KB of fragment buffers

    prep_w0 <<<dim3(64),  dim3(256), 0, stream>>>(w0, wf + WS_W0H, wf + WS_W0L);
    prep_whd<<<dim3(256), dim3(256), 0, stream>>>(w1, wf + WS_W1H, wf + WS_W1L);
    prep_whd<<<dim3(256), dim3(256), 0, stream>>>(w2, wf + WS_W2H, wf + WS_W2L);

    mlp_kernel<<<dim3(NPOSE * BPTS / TM), dim3(512), 0, stream>>>(
        x_world, inv_poses, b0, b1, b2, w3, b3, wf, out);
    select_kernel<<<dim3(BPTS / 256), dim3(256), 0, stream>>>(
        x_world, inv_poses, vector, out);
}

// Round 7
// 384.442 us; speedup vs baseline: 22.1013x; 1.9173x over previous
//
#include <hip/hip_runtime.h>
#include <cmath>

namespace {
constexpr int BPTS  = 16384;
constexpr int NPOSE = 32;
constexpr int KV    = 8;
constexpr int HD    = 256;
constexpr int TM    = 64;       // points per block

constexpr size_t OFF_XLOCAL = 0;
constexpr size_t OFF_XLA    = (size_t)BPTS * 3;
constexpr size_t OFF_MINENC = OFF_XLA + (size_t)NPOSE * BPTS * 3;
constexpr size_t OFF_POSEQ  = OFF_MINENC + (size_t)BPTS * NPOSE;
constexpr size_t OFF_CLASS  = OFF_POSEQ + (size_t)BPTS * 16;
constexpr size_t OFF_PRED   = OFF_CLASS + (size_t)BPTS;
constexpr size_t OFF_VECQ   = OFF_PRED + (size_t)BPTS * NPOSE;

// workspace (f16 elements): weight fragment buffers, hi/lo split
constexpr size_t WS_W0H = 0;         // 16 cht * 2 kc * 64 lanes * 8 e
constexpr size_t WS_W0L = 16384;
constexpr size_t WS_W1H = 32768;     // 16 cht * 8 kc * 512
constexpr size_t WS_W1L = 98304;
constexpr size_t WS_W2H = 163840;
constexpr size_t WS_W2L = 229376;
}

typedef _Float16 f16;
typedef __attribute__((ext_vector_type(4))) _Float16 f16x4;
typedef __attribute__((ext_vector_type(8))) _Float16 f16x8;
typedef __attribute__((ext_vector_type(4))) float    f32x4;

#define MFMA16(a, b, c) __builtin_amdgcn_mfma_f32_16x16x32_f16((a), (b), (c), 0, 0, 0)

// ---- weight prep: split fp32 W[k][ch] into hi/lo f16 A-fragments.
// Fragment layout: idx = ((cht*KC + kc)*64 + lane)*8 + e, holding
// W[k = kc*32 + (lane>>4)*8 + e][ch = cht*16 + (lane&15)].
// Convention (m = lane&15, k = (lane>>4)*8+e) HW-verified by round-4/6 passes.
__global__ __launch_bounds__(256)
void prep_w0(const float* __restrict__ w, f16* __restrict__ dh, f16* __restrict__ dl)
{
    int i = blockIdx.x * 256 + threadIdx.x;      // 16384 total
    int e  = i & 7;
    int l  = (i >> 3) & 63;
    int kc = (i >> 9) & 1;
    int nt = i >> 10;
    int k   = kc * 32 + ((l >> 4) << 3) + e;
    int col = nt * 16 + (l & 15);
    float v = (k < 39) ? w[k * HD + col] : 0.f;
    f16 hi = (f16)v;
    dh[i] = hi;
    dl[i] = (f16)(v - (float)hi);
}

__global__ __launch_bounds__(256)
void prep_whd(const float* __restrict__ w, f16* __restrict__ dh, f16* __restrict__ dl)
{
    int i = blockIdx.x * 256 + threadIdx.x;      // 65536 total
    int e  = i & 7;
    int l  = (i >> 3) & 63;
    int kc = (i >> 9) & 7;
    int nt = i >> 12;
    int k   = kc * 32 + ((l >> 4) << 3) + e;
    int col = nt * 16 + (l & 15);
    float v = w[k * HD + col];
    f16 hi = (f16)v;
    dh[i] = hi;
    dl[i] = (f16)(v - (float)hi);
}

// swizzled byte address inside the 128-col half-plane: row p (0..63), cbyte 0..255
__device__ __forceinline__ int bswz(int p, int cbyte) {
    return p * 256 + (cbyte ^ ((p & 7) << 4));
}

__global__ __launch_bounds__(512, 4)
void mlp_kernel(const float* __restrict__ x_world,
                const float* __restrict__ inv_poses,
                const float* __restrict__ b0, const float* __restrict__ b1,
                const float* __restrict__ b2, const float* __restrict__ w3,
                const float* __restrict__ b3, const f16* __restrict__ wf,
                float* __restrict__ out)
{
    __shared__ char  lds[32768];        // bufh [0,16K) | bufl [16K,32K); feat overlaps head
    __shared__ float predp[TM][8];      // separate: written while other waves still read buf

    f16* feath = (f16*)lds;             // [64][40] f16 = 5 KB
    f16* featl = (f16*)(lds + 5120);    // 5 KB

    const int tid  = threadIdx.x;
    const int lane = tid & 63;
    const int wv   = tid >> 6;          // wave id 0..7 = channel group
    const int l15  = lane & 15;
    const int g    = lane >> 4;

    const int bid   = blockIdx.x;
    const int n_idx = bid >> 8;         // 256 blocks per pose
    const int bbase = (bid & 255) * TM;

    // wave wv owns cht = wv (phase A, cols 0..127) and wv+8 (phase B, cols 128..255)
    // for ALL 64 points: weight fragments read exactly once per block (no wave dup).

    // ---- pose transform + positional encoding (8 threads per point) ----
    {
        const int p   = tid >> 3;       // 0..63
        const int sub = tid & 7;
        const int b   = bbase + p;
        const float xw0 = x_world[b*3+0], xw1 = x_world[b*3+1], xw2 = x_world[b*3+2];
        const float* P = inv_poses + n_idx * 16;
        float xl[3];
        #pragma unroll
        for (int x = 0; x < 3; ++x)
            xl[x] = P[x*4+3] + P[x*4+0]*xw0 + P[x*4+1]*xw1 + P[x*4+2]*xw2;

        auto put = [&](int c, float v) {
            f16 hi = (f16)v;
            feath[p*40 + c] = hi;
            featl[p*40 + c] = (f16)(v - (float)hi);
        };
        if (sub == 0) {
            float* xla = out + OFF_XLA + ((size_t)n_idx * BPTS + b) * 3;
            #pragma unroll
            for (int x = 0; x < 3; ++x) { xla[x] = xl[x]; put(x, xl[x]); }
            put(39, 0.f);               // k-pad
        }
        #pragma unroll
        for (int t = 0; t < 2; ++t) {   // 12 sin/cos jobs: j = sub, and j = sub+8 (sub<4)
            int j = sub + 8*t;
            if (j < 12) {
                int o = j >> 1, fn = j & 1;
                float s = (float)(1 << o);
                #pragma unroll
                for (int x = 0; x < 3; ++x) {
                    float a = xl[x] * s;
                    put(3 + 6*o + 3*fn + x, fn ? cosf(a) : sinf(a));
                }
            }
        }
    }
    __syncthreads();

    f32x4 acc[2][4];                    // [c2][pt]: 32 channels x 64 points (32 VGPR)

    auto init_bias = [&](const float* bias) {
        #pragma unroll
        for (int c2 = 0; c2 < 2; ++c2) {
            f32x4 bv = *(const f32x4*)(bias + (wv + c2*8) * 16 + g * 4);
            #pragma unroll
            for (int pt = 0; pt < 4; ++pt) acc[c2][pt] = bv;
        }
    };

    // ---- layer 0: feat(39, padded 64) -> acc ----
    init_bias(b0);
    {
        const f16x8 z = {};
        #pragma unroll
        for (int kc = 0; kc < 2; ++kc) {
            f16x8 ah[4], al[4];
            #pragma unroll
            for (int pt = 0; pt < 4; ++pt) {
                int p = pt * 16 + l15;
                if (kc == 0) {
                    ah[pt] = *(const f16x8*)&feath[p*40 + g*8];
                    al[pt] = *(const f16x8*)&featl[p*40 + g*8];
                } else if (g == 0) {
                    ah[pt] = *(const f16x8*)&feath[p*40 + 32];
                    al[pt] = *(const f16x8*)&featl[p*40 + 32];
                } else { ah[pt] = z; al[pt] = z; }
            }
            #pragma unroll
            for (int c2 = 0; c2 < 2; ++c2) {
                int off = (((wv + c2*8) * 2 + kc) * 64 + lane) * 8;
                f16x8 wh = *(const f16x8*)(wf + WS_W0H + off);
                f16x8 wl = *(const f16x8*)(wf + WS_W0L + off);
                #pragma unroll
                for (int pt = 0; pt < 4; ++pt) {
                    acc[c2][pt] = MFMA16(wh, ah[pt], acc[c2][pt]);
                    acc[c2][pt] = MFMA16(wl, ah[pt], acc[c2][pt]);
                    acc[c2][pt] = MFMA16(wh, al[pt], acc[c2][pt]);
                }
            }
        }
    }

    auto packpair = [&](f32x4 a, f16x4& hvv, f16x4& lvv) {
        float v0 = fmaxf(a[0], 0.f), v1 = fmaxf(a[1], 0.f);
        float v2 = fmaxf(a[2], 0.f), v3 = fmaxf(a[3], 0.f);
        f16 h0 = (f16)v0, h1 = (f16)v1, h2 = (f16)v2, h3 = (f16)v3;
        hvv = (f16x4){h0, h1, h2, h3};
        lvv = (f16x4){(f16)(v0 - (float)h0), (f16)(v1 - (float)h1),
                      (f16)(v2 - (float)h2), (f16)(v3 - (float)h3)};
    };
    // store 4 consecutive channels (g*4 within cht tile wv) for point pt*16+l15
    auto stfrag = [&](int pt, f16x4 hvv, f16x4 lvv) {
        int byte = bswz(pt * 16 + l15, wv * 32 + g * 8);   // (cht&7) == wv both phases
        *(f16x4*)(lds + byte)         = hvv;
        *(f16x4*)(lds + 16384 + byte) = lvv;
    };
    auto phase = [&](const f16* wfh, const f16* wfl, int ph) {
        #pragma unroll
        for (int kc4 = 0; kc4 < 4; ++kc4) {
            f16x8 bh[4], bl[4];
            #pragma unroll
            for (int pt = 0; pt < 4; ++pt) {
                int byte = bswz(pt * 16 + l15, kc4 * 64 + g * 16);
                bh[pt] = *(const f16x8*)(lds + byte);
                bl[pt] = *(const f16x8*)(lds + 16384 + byte);
            }
            int kcg = ph * 4 + kc4;
            #pragma unroll
            for (int c2 = 0; c2 < 2; ++c2) {
                int off = (((wv + c2*8) * 8 + kcg) * 64 + lane) * 8;
                f16x8 wh = *(const f16x8*)(wfh + off);
                f16x8 wl = *(const f16x8*)(wfl + off);
                #pragma unroll
                for (int pt = 0; pt < 4; ++pt) {
                    acc[c2][pt] = MFMA16(wh, bh[pt], acc[c2][pt]);
                    acc[c2][pt] = MFMA16(wl, bh[pt], acc[c2][pt]);
                    acc[c2][pt] = MFMA16(wh, bl[pt], acc[c2][pt]);
                }
            }
        }
    };

    // ---- hidden layer: acc(h_prev) -> stores -> acc(h_next), two k-phases ----
    auto hd_layer = [&](const float* bias, const f16* wfh, const f16* wfl) {
        f16x4 hh[4], hl[4];                       // held: phase-B channels (8 VGPR)
        #pragma unroll
        for (int pt = 0; pt < 4; ++pt)
            packpair(acc[1][pt], hh[pt], hl[pt]);
        __syncthreads();                          // prior buf/feat reads done
        #pragma unroll
        for (int pt = 0; pt < 4; ++pt) {          // store phase-A channels (cols 0..127)
            f16x4 a, b;
            packpair(acc[0][pt], a, b);
            stfrag(pt, a, b);
        }
        __syncthreads();
        init_bias(bias);
        phase(wfh, wfl, 0);                       // consume cols 0..127
        __syncthreads();                          // phase-A reads done
        #pragma unroll
        for (int pt = 0; pt < 4; ++pt)            // store phase-B channels (cols 128..255)
            stfrag(pt, hh[pt], hl[pt]);
        __syncthreads();
        phase(wfh, wfl, 1);                       // consume cols 128..255
    };

    hd_layer(b1, wf + WS_W1H, wf + WS_W1L);
    hd_layer(b2, wf + WS_W2H, wf + WS_W2L);

    // ---- layer 3 from registers: pred[point] = sum_ch relu(h2)*w3[ch] ----
    {
        float pp[4] = {0.f, 0.f, 0.f, 0.f};
        #pragma unroll
        for (int c2 = 0; c2 < 2; ++c2) {
            f32x4 wvv = *(const f32x4*)(w3 + (wv + c2*8) * 16 + g * 4);
            #pragma unroll
            for (int pt = 0; pt < 4; ++pt)
                #pragma unroll
                for (int r = 0; r < 4; ++r)
                    pp[pt] = fmaf(fmaxf(acc[c2][pt][r], 0.f), wvv[r], pp[pt]);
        }
        #pragma unroll
        for (int pt = 0; pt < 4; ++pt) {          // reduce over g (channel sub-groups)
            pp[pt] += __shfl_xor(pp[pt], 16);
            pp[pt] += __shfl_xor(pp[pt], 32);
        }
        if (g == 0) {
            #pragma unroll
            for (int pt = 0; pt < 4; ++pt)
                predp[pt * 16 + l15][wv] = pp[pt];
        }
    }
    __syncthreads();
    if (tid < TM) {
        float s = b3[0];
        #pragma unroll
        for (int j = 0; j < 8; ++j) s += predp[tid][j];
        out[OFF_PRED + (size_t)(bbase + tid) * NPOSE + n_idx] = s;
    }
}

__global__ __launch_bounds__(256)
void select_kernel(const float* __restrict__ x_world,
                   const float* __restrict__ inv_poses,
                   const float* __restrict__ vector,
                   float* __restrict__ out)
{
    const int b = blockIdx.x * 256 + threadIdx.x;
    if (b >= BPTS) return;

    const float* pr = out + OFF_PRED + (size_t)b * NPOSE;
    float best = pr[0];
    int idx = 0;
    #pragma unroll
    for (int n = 1; n < NPOSE; ++n) {           // first-occurrence min == jnp.argmin
        float v = pr[n];
        if (v < best) { best = v; idx = n; }
    }

    float* me = out + OFF_MINENC + (size_t)b * NPOSE;
    #pragma unroll
    for (int n = 0; n < NPOSE; ++n) me[n] = (n == idx) ? 1.f : 0.f;

    const float* P = inv_poses + idx * 16;
    float* pq = out + OFF_POSEQ + (size_t)b * 16;
    #pragma unroll
    for (int m = 0; m < 16; ++m) pq[m] = P[m];

    const float xw0 = x_world[b*3+0], xw1 = x_world[b*3+1], xw2 = x_world[b*3+2];
    float* xl = out + OFF_XLOCAL + (size_t)b * 3;
    #pragma unroll
    for (int x = 0; x < 3; ++x)
        xl[x] = P[x*4+3] + P[x*4+0]*xw0 + P[x*4+1]*xw1 + P[x*4+2]*xw2;

    out[OFF_CLASS + b] = (float)idx;

    const float* vq = vector + idx * KV;
    float* ov = out + OFF_VECQ + (size_t)b * KV;
    #pragma unroll
    for (int m = 0; m < KV; ++m) ov[m] = vq[m];
}

extern "C" void kernel_launch(void* const* d_in, const int* in_sizes, int n_in,
                              void* d_out, int out_size, void* d_ws, size_t ws_size,
                              hipStream_t stream)
{
    const float* x_world   = (const float*)d_in[0];
    const float* inv_poses = (const float*)d_in[1];
    const float* vector    = (const float*)d_in[2];
    const float* w0 = (const float*)d_in[3];
    const float* b0 = (const float*)d_in[4];
    const float* w1 = (const float*)d_in[5];
    const float* b1 = (const float*)d_in[6];
    const float* w2 = (const float*)d_in[7];
    const float* b2 = (const float*)d_in[8];
    const float* w3 = (const float*)d_in[9];
    const float* b3 = (const float*)d_in[10];
    float* out = (float*)d_out;
    f16*   wf  = (f16*)d_ws;            // 576 KB of fragment buffers

    prep_w0 <<<dim3(64),  dim3(256), 0, stream>>>(w0, wf + WS_W0H, wf + WS_W0L);
    prep_whd<<<dim3(256), dim3(256), 0, stream>>>(w1, wf + WS_W1H, wf + WS_W1L);
    prep_whd<<<dim3(256), dim3(256), 0, stream>>>(w2, wf + WS_W2H, wf + WS_W2L);

    mlp_kernel<<<dim3(NPOSE * BPTS / TM), dim3(512), 0, stream>>>(
        x_world, inv_poses, b0, b1, b2, w3, b3, wf, out);
    select_kernel<<<dim3(BPTS / 256), dim3(256), 0, stream>>>(
        x_world, inv_poses, vector, out);
}